// Round 1
// baseline (628.665 us; speedup 1.0000x reference)
//
#include <hip/hip_runtime.h>

// ---------------------------------------------------------------------------
// BERT layer (attn + top-1 MoE FFN) for MI355X / gfx950.
// B=16 S=512 H=1024 I=4096 NH=16 DH=64 E=8.  bf16 MFMA (16x16x32), fp32 accum.
// Pipeline: cvt x -> transpose weights -> QKV GEMMs -> flash attn (swapped
// S^T=K*Q^T) -> O-proj+resid -> LN1 -> LN2+colsum -> router/argmax -> MoE up
// (gelu) -> MoE down (+resid) -> d_out.  Router path kept fp32 so argmax
// matches the fp32 reference.
// ---------------------------------------------------------------------------

typedef __attribute__((ext_vector_type(4))) float f32x4;
typedef __attribute__((ext_vector_type(8))) short s8v;   // 8 x bf16 bits
typedef __attribute__((ext_vector_type(4))) short s4v;   // 4 x bf16 bits
typedef unsigned short u16;

#define DEV static __device__ __forceinline__

DEV u16 f2bf(float f){
  union { float f; unsigned u; } v; v.f = f;
  unsigned r = v.u + 0x7fffu + ((v.u >> 16) & 1u);   // RNE
  return (u16)(r >> 16);
}

DEV f32x4 mfma16(s8v a, s8v b, f32x4 c){
  return __builtin_amdgcn_mfma_f32_16x16x32_bf16(a, b, c, 0, 0, 0);
}

DEV float wave_sum(float s){
#pragma unroll
  for (int o = 1; o < 64; o <<= 1) s += __shfl_xor(s, o);
  return s;
}

#define ASYNC_COPY16(g, l) \
  __builtin_amdgcn_global_load_lds((const __attribute__((address_space(1))) void*)(g), \
                                   (__attribute__((address_space(3))) void*)(l), 16, 0, 0)

// ---------------------------------------------------------------------------
// fp32 [n*8] -> bf16
__global__ __launch_bounds__(256) void cvt_bf16(const float* __restrict__ in,
                                                u16* __restrict__ out)
{
  const size_t i = ((size_t)blockIdx.x * 256 + threadIdx.x) * 8;
  f32x4 a = *(const f32x4*)&in[i];
  f32x4 b = *(const f32x4*)&in[i + 4];
  s8v o;
#pragma unroll
  for (int j = 0; j < 4; ++j){ o[j] = (short)f2bf(a[j]); o[4 + j] = (short)f2bf(b[j]); }
  *(s8v*)&out[i] = o;
}

// fp32 [R][C] -> bf16 [C][R]   (batched via blockIdx.z, stride R*C)
__global__ __launch_bounds__(256) void transpose_w(const float* __restrict__ in,
                                                   u16* __restrict__ out, int R, int C)
{
  __shared__ float t[32][33];
  const size_t bs = (size_t)blockIdx.z * R * (size_t)C;
  in += bs; out += bs;
  const int c0 = blockIdx.x * 32, r0 = blockIdx.y * 32;
  const int tx = threadIdx.x & 31, ty = threadIdx.x >> 5;   // 32 x 8
#pragma unroll
  for (int j = 0; j < 32; j += 8) t[ty + j][tx] = in[(size_t)(r0 + ty + j) * C + c0 + tx];
  __syncthreads();
#pragma unroll
  for (int j = 0; j < 32; j += 8) out[(size_t)(c0 + ty + j) * R + r0 + tx] = f2bf(t[tx][ty + j]);
}

// ---------------------------------------------------------------------------
// C = A[M,K](bf16) * Bt[N,K]^T(bf16) + bias;   128x128 tile, 4 waves, BK=32.
// MODE 0: bf16 out   1: gelu->bf16 out   2: fp32 out + residual
// MODE 3: bf16 scatter to vt[b][h][d][s]  (B=16,NH=16,DH=64,S=512)
template<int MODE>
__global__ __launch_bounds__(256, 2) void gemm_bt(
    const u16* __restrict__ A, const u16* __restrict__ Bt,
    const float* __restrict__ bias, void* __restrict__ outp,
    const float* __restrict__ resid, int M, int N, int K,
    const int* __restrict__ choice,
    long aBatch, long outBatch, long residBatch, long btExpert, long biasExpert)
{
  const int z = blockIdx.z;
  if (choice){
    const int e = choice[z];
    Bt   += (size_t)e * btExpert;
    bias += (size_t)e * biasExpert;
  }
  A += (size_t)z * aBatch;

  const int tid = threadIdx.x;
  const int lane = tid & 63, wid = tid >> 6;
  const int hi = lane >> 4, l15 = lane & 15;
  const int wr = wid >> 1, wc = wid & 1;
  const long row0 = (long)blockIdx.x * 128;
  const long col0 = (long)blockIdx.y * 128;

  __shared__ __align__(16) u16 lA[128 * 32];
  __shared__ __align__(16) u16 lB[128 * 32];

  f32x4 acc[4][4];
#pragma unroll
  for (int i = 0; i < 4; ++i)
#pragma unroll
    for (int j = 0; j < 4; ++j) acc[i][j] = f32x4{0.f, 0.f, 0.f, 0.f};

  const int c1 = tid, c2 = tid + 256;
  const u16* sA1 = A  + (row0 + (c1 >> 2)) * (size_t)K + (c1 & 3) * 8;
  const u16* sA2 = A  + (row0 + (c2 >> 2)) * (size_t)K + (c2 & 3) * 8;
  const u16* sB1 = Bt + (col0 + (c1 >> 2)) * (size_t)K + (c1 & 3) * 8;
  const u16* sB2 = Bt + (col0 + (c2 >> 2)) * (size_t)K + (c2 & 3) * 8;
  u16* dA1 = &lA[c1 * 8]; u16* dA2 = &lA[c2 * 8];
  u16* dB1 = &lB[c1 * 8]; u16* dB2 = &lB[c2 * 8];

  for (int kt = 0; kt < K; kt += 32){
    ASYNC_COPY16(sA1, dA1);
    ASYNC_COPY16(sA2, dA2);
    ASYNC_COPY16(sB1, dB1);
    ASYNC_COPY16(sB2, dB2);
    sA1 += 32; sA2 += 32; sB1 += 32; sB2 += 32;
    asm volatile("s_waitcnt vmcnt(0)" ::: "memory");
    __syncthreads();

    s8v af[4], bf[4];
#pragma unroll
    for (int mi = 0; mi < 4; ++mi)
      af[mi] = *(const s8v*)&lA[(wr * 64 + mi * 16 + l15) * 32 + hi * 8];
#pragma unroll
    for (int ni = 0; ni < 4; ++ni)
      bf[ni] = *(const s8v*)&lB[(wc * 64 + ni * 16 + l15) * 32 + hi * 8];
#pragma unroll
    for (int mi = 0; mi < 4; ++mi)
#pragma unroll
      for (int ni = 0; ni < 4; ++ni)
        acc[mi][ni] = mfma16(af[mi], bf[ni], acc[mi][ni]);
    __syncthreads();
  }

#pragma unroll
  for (int mi = 0; mi < 4; ++mi){
    const long rowb = row0 + wr * 64 + mi * 16 + hi * 4;
#pragma unroll
    for (int ni = 0; ni < 4; ++ni){
      const long col = col0 + wc * 64 + ni * 16 + l15;
      const float bv = bias[col];
#pragma unroll
      for (int r = 0; r < 4; ++r){
        const long row = rowb + r;
        float v = acc[mi][ni][r] + bv;
        if (MODE == 2){
          float* o = (float*)outp + (size_t)z * outBatch;
          const float* rs = resid + (size_t)z * residBatch;
          o[row * N + col] = v + rs[row * N + col];
        } else if (MODE == 0){
          u16* o = (u16*)outp + (size_t)z * outBatch;
          o[row * N + col] = f2bf(v);
        } else if (MODE == 1){
          u16* o = (u16*)outp + (size_t)z * outBatch;
          const float gv = 0.5f * v * (1.0f + erff(v * 0.70710678118654752f));
          o[row * N + col] = f2bf(gv);
        } else {                       // MODE 3: vt[b][h][d][s]
          const int bb = (int)(row >> 9), ss = (int)(row & 511);
          const int hh = (int)(col >> 6), dd = (int)(col & 63);
          ((u16*)outp)[(((size_t)(bb * 16 + hh)) * 64 + dd) * 512 + ss] = f2bf(v);
        }
      }
    }
  }
}

// ---------------------------------------------------------------------------
// Flash attention, swapped form: S^T = K*Q^T so softmax state is per-lane (q =
// lane&15).  One wave per 16-q tile; 32 keys/iter; P^T through padded LDS.
__global__ __launch_bounds__(256, 2) void attn_fwd(
    const u16* __restrict__ qb, const u16* __restrict__ kb,
    const u16* __restrict__ vt, u16* __restrict__ ctx)
{
  const int lane = threadIdx.x & 63, wid = threadIdx.x >> 6;
  const int hi = lane >> 4, l15 = lane & 15;
  const int h = blockIdx.y, b = blockIdx.z;
  const int q0 = blockIdx.x * 64 + wid * 16;

  const u16* qp  = qb + ((size_t)b * 512 + q0) * 1024 + h * 64;
  const u16* kp0 = kb + (size_t)b * 512 * 1024 + h * 64;
  const u16* vp  = vt + ((size_t)(b * 16 + h)) * 64 * 512;

  __shared__ __align__(16) u16 P[4][16][40];   // [wave][q][32 keys + pad]

  const s8v qf0 = *(const s8v*)&qp[(size_t)l15 * 1024 + hi * 8];
  const s8v qf1 = *(const s8v*)&qp[(size_t)l15 * 1024 + 32 + hi * 8];

  f32x4 o[4];
#pragma unroll
  for (int mi = 0; mi < 4; ++mi) o[mi] = f32x4{0.f, 0.f, 0.f, 0.f};
  float mrun = -3e38f, lrun = 0.f;

  for (int k0 = 0; k0 < 512; k0 += 32){
    const u16* kp = kp0 + (size_t)k0 * 1024;
    f32x4 s0 = f32x4{0.f,0.f,0.f,0.f}, s1 = f32x4{0.f,0.f,0.f,0.f};
    s0 = mfma16(*(const s8v*)&kp[(size_t)l15 * 1024 + hi * 8],             qf0, s0);
    s0 = mfma16(*(const s8v*)&kp[(size_t)l15 * 1024 + 32 + hi * 8],        qf1, s0);
    s1 = mfma16(*(const s8v*)&kp[(size_t)(16 + l15) * 1024 + hi * 8],      qf0, s1);
    s1 = mfma16(*(const s8v*)&kp[(size_t)(16 + l15) * 1024 + 32 + hi * 8], qf1, s1);

    float mx = fmaxf(fmaxf(fmaxf(s0[0], s0[1]), fmaxf(s0[2], s0[3])),
                     fmaxf(fmaxf(s1[0], s1[1]), fmaxf(s1[2], s1[3]))) * 0.125f;
    mx = fmaxf(mx, __shfl_xor(mx, 16));
    mx = fmaxf(mx, __shfl_xor(mx, 32));
    const float mnew = fmaxf(mrun, mx);
    const float alpha = __expf(mrun - mnew);
    mrun = mnew;

    float p[8]; float ps = 0.f;
#pragma unroll
    for (int r = 0; r < 4; ++r){ p[r]     = __expf(s0[r] * 0.125f - mnew); ps += p[r]; }
#pragma unroll
    for (int r = 0; r < 4; ++r){ p[4 + r] = __expf(s1[r] * 0.125f - mnew); ps += p[4 + r]; }
    ps += __shfl_xor(ps, 16);
    ps += __shfl_xor(ps, 32);
    lrun = lrun * alpha + ps;
#pragma unroll
    for (int mi = 0; mi < 4; ++mi)
#pragma unroll
      for (int r = 0; r < 4; ++r) o[mi][r] *= alpha;

    s4v pk0, pk1;
#pragma unroll
    for (int r = 0; r < 4; ++r){ pk0[r] = (short)f2bf(p[r]); pk1[r] = (short)f2bf(p[4 + r]); }
    *(s4v*)&P[wid][l15][4 * hi]      = pk0;   // keys k0 + 4*hi + r
    *(s4v*)&P[wid][l15][16 + 4 * hi] = pk1;   // keys k0 + 16 + 4*hi + r

    const s8v pf = *(const s8v*)&P[wid][l15][8 * hi];   // keys k0+8*hi+i, q=l15
#pragma unroll
    for (int mi = 0; mi < 4; ++mi)
      o[mi] = mfma16(*(const s8v*)&vp[(size_t)(mi * 16 + l15) * 512 + k0 + 8 * hi], pf, o[mi]);
  }

  const float inv = 1.f / lrun;
  u16* cp = ctx + ((size_t)b * 512 + q0 + l15) * 1024 + h * 64;
#pragma unroll
  for (int mi = 0; mi < 4; ++mi)
#pragma unroll
    for (int r = 0; r < 4; ++r)
      cp[mi * 16 + 4 * hi + r] = f2bf(o[mi][r] * inv);
}

// ---------------------------------------------------------------------------
// LayerNorm in place (fp32), one wave per 1024-col row.
__global__ __launch_bounds__(256, 2) void ln_inplace(float* __restrict__ x,
    const float* __restrict__ g, const float* __restrict__ be)
{
  const int row = blockIdx.x * 4 + (threadIdx.x >> 6);
  const int lane = threadIdx.x & 63;
  float* p = x + (size_t)row * 1024;
  f32x4 v[4];
#pragma unroll
  for (int c = 0; c < 4; ++c) v[c] = *(const f32x4*)&p[c * 256 + lane * 4];
  float s = 0.f;
#pragma unroll
  for (int c = 0; c < 4; ++c){ s += v[c][0] + v[c][1] + v[c][2] + v[c][3]; }
  const float mu = wave_sum(s) * (1.f / 1024.f);
  float s2 = 0.f;
#pragma unroll
  for (int c = 0; c < 4; ++c)
#pragma unroll
    for (int j = 0; j < 4; ++j){ const float d = v[c][j] - mu; s2 += d * d; }
  const float rs = rsqrtf(wave_sum(s2) * (1.f / 1024.f) + 1e-12f);
#pragma unroll
  for (int c = 0; c < 4; ++c){
    const f32x4 gg = *(const f32x4*)&g[c * 256 + lane * 4];
    const f32x4 bb = *(const f32x4*)&be[c * 256 + lane * 4];
    f32x4 ov;
#pragma unroll
    for (int j = 0; j < 4; ++j) ov[j] = (v[c][j] - mu) * rs * gg[j] + bb[j];
    *(f32x4*)&p[c * 256 + lane * 4] = ov;
  }
}

// LN2 -> bf16 x_ln, plus fp32 per-(b,col) column sums for the router.
__global__ __launch_bounds__(256, 2) void ln2_colsum(
    const float* __restrict__ attn, const float* __restrict__ g, const float* __restrict__ be,
    u16* __restrict__ xln, float* __restrict__ colsum)
{
  const int b = blockIdx.y;
  const int wid = threadIdx.x >> 6, lane = threadIdx.x & 63;
  __shared__ float cacc[1024];
  for (int i = threadIdx.x; i < 1024; i += 256) cacc[i] = 0.f;
  __syncthreads();
  float acc[16];
#pragma unroll
  for (int i = 0; i < 16; ++i) acc[i] = 0.f;
  const int rbase = b * 512 + blockIdx.x * 64 + wid * 16;
  for (int rr = 0; rr < 16; ++rr){
    const float* p = attn + (size_t)(rbase + rr) * 1024;
    f32x4 v[4];
#pragma unroll
    for (int c = 0; c < 4; ++c) v[c] = *(const f32x4*)&p[c * 256 + lane * 4];
    float s = 0.f;
#pragma unroll
    for (int c = 0; c < 4; ++c) s += v[c][0] + v[c][1] + v[c][2] + v[c][3];
    const float mu = wave_sum(s) * (1.f / 1024.f);
    float s2 = 0.f;
#pragma unroll
    for (int c = 0; c < 4; ++c)
#pragma unroll
      for (int j = 0; j < 4; ++j){ const float d = v[c][j] - mu; s2 += d * d; }
    const float rs = rsqrtf(wave_sum(s2) * (1.f / 1024.f) + 1e-12f);
    u16* op = xln + (size_t)(rbase + rr) * 1024;
#pragma unroll
    for (int c = 0; c < 4; ++c){
      const f32x4 gg = *(const f32x4*)&g[c * 256 + lane * 4];
      const f32x4 bb = *(const f32x4*)&be[c * 256 + lane * 4];
      s4v ov;
#pragma unroll
      for (int j = 0; j < 4; ++j){
        const float y = (v[c][j] - mu) * rs * gg[j] + bb[j];
        acc[c * 4 + j] += y;
        ov[j] = (short)f2bf(y);
      }
      *(s4v*)&op[c * 256 + lane * 4] = ov;
    }
  }
#pragma unroll
  for (int c = 0; c < 4; ++c)
#pragma unroll
    for (int j = 0; j < 4; ++j)
      atomicAdd(&cacc[c * 256 + lane * 4 + j], acc[c * 4 + j]);
  __syncthreads();
  for (int i = threadIdx.x; i < 1024; i += 256) atomicAdd(&colsum[b * 1024 + i], cacc[i]);
}

// logits[b][e] = (1/S) * sum_h colsum[b][h]*gate[h][e]; argmax -> choice.
__global__ void router_argmax(const float* __restrict__ colsum, const float* __restrict__ gate,
                              float* __restrict__ logits, int* __restrict__ choice)
{
  const int b = blockIdx.x, lane = threadIdx.x;   // 64 threads
  float pa[8];
#pragma unroll
  for (int e = 0; e < 8; ++e) pa[e] = 0.f;
  for (int it = 0; it < 16; ++it){
    const int hh = it * 64 + lane;
    const float c = colsum[b * 1024 + hh];
    const float* gp = gate + (size_t)hh * 8;
#pragma unroll
    for (int e = 0; e < 8; ++e) pa[e] += c * gp[e];
  }
#pragma unroll
  for (int e = 0; e < 8; ++e) pa[e] = wave_sum(pa[e]);
  if (lane == 0){
    float best = -3e38f; int bi = 0;
#pragma unroll
    for (int e = 0; e < 8; ++e){
      const float lg = pa[e] * (1.f / 512.f);
      logits[b * 8 + e] = lg;
      if (lg > best){ best = lg; bi = e; }   // strict > keeps first max (jnp.argmax)
    }
    choice[b] = bi;
  }
}

// ---------------------------------------------------------------------------
extern "C" void kernel_launch(void* const* d_in, const int* in_sizes, int n_in,
                              void* d_out, int out_size, void* d_ws, size_t ws_size,
                              hipStream_t stream)
{
  const float* x    = (const float*)d_in[0];
  const float* Wq   = (const float*)d_in[1];
  const float* bq   = (const float*)d_in[2];
  const float* Wk   = (const float*)d_in[3];
  const float* bk   = (const float*)d_in[4];
  const float* Wv   = (const float*)d_in[5];
  const float* bv   = (const float*)d_in[6];
  const float* Wo   = (const float*)d_in[7];
  const float* bo   = (const float*)d_in[8];
  const float* ln1g = (const float*)d_in[9];
  const float* ln1b = (const float*)d_in[10];
  const float* ln2g = (const float*)d_in[11];
  const float* ln2b = (const float*)d_in[12];
  const float* gate = (const float*)d_in[13];
  const float* Wup  = (const float*)d_in[14];
  const float* bup  = (const float*)d_in[15];
  const float* Wdn  = (const float*)d_in[16];
  const float* bdn  = (const float*)d_in[17];

  size_t off = 0;
  char* wsb = (char*)d_ws;
  auto take = [&](size_t n) -> void* {
    void* p = wsb + off; off += (n + 255) & ~(size_t)255; return p;
  };
  u16*   x_bf  = (u16*)take(8192ull * 1024 * 2);          // later: ctx
  u16*   Wqt   = (u16*)take(1024ull * 1024 * 2);
  u16*   Wkt   = (u16*)take(1024ull * 1024 * 2);
  u16*   Wvt   = (u16*)take(1024ull * 1024 * 2);
  u16*   Wot   = (u16*)take(1024ull * 1024 * 2);
  u16*   q_bf  = (u16*)take(8192ull * 1024 * 2);          // later: x_ln
  u16*   k_bf  = (u16*)take(8192ull * 1024 * 2);
  u16*   vt_bf = (u16*)take(8192ull * 1024 * 2);
  float* tmp   = (float*)take(8192ull * 1024 * 4);        // pre-LN1 -> attn_out
  u16*   Wupt  = (u16*)take(8ull * 4096 * 1024 * 2);
  u16*   Wdnt  = (u16*)take(8ull * 1024 * 4096 * 2);
  u16*   h_bf  = (u16*)take(8192ull * 4096 * 2);
  float* colsum = (float*)take(16ull * 1024 * 4);
  int*   choice = (int*)take(256);

  u16* ctx = x_bf;     // x_bf dead after QKV GEMMs
  u16* xln = q_bf;     // q_bf dead after attention
  float* logits = (float*)d_out + 8388608;

  // 1. convert + transpose
  cvt_bf16<<<4096, 256, 0, stream>>>(x, x_bf);
  transpose_w<<<dim3(32, 32, 1),  256, 0, stream>>>(Wq,  Wqt,  1024, 1024);
  transpose_w<<<dim3(32, 32, 1),  256, 0, stream>>>(Wk,  Wkt,  1024, 1024);
  transpose_w<<<dim3(32, 32, 1),  256, 0, stream>>>(Wv,  Wvt,  1024, 1024);
  transpose_w<<<dim3(32, 32, 1),  256, 0, stream>>>(Wo,  Wot,  1024, 1024);
  transpose_w<<<dim3(128, 32, 8), 256, 0, stream>>>(Wup, Wupt, 1024, 4096);
  transpose_w<<<dim3(32, 128, 8), 256, 0, stream>>>(Wdn, Wdnt, 4096, 1024);

  // 2. QKV projections
  gemm_bt<0><<<dim3(64, 8, 1), 256, 0, stream>>>(x_bf, Wqt, bq, q_bf,  nullptr,
      8192, 1024, 1024, nullptr, 0, 0, 0, 0, 0);
  gemm_bt<0><<<dim3(64, 8, 1), 256, 0, stream>>>(x_bf, Wkt, bk, k_bf,  nullptr,
      8192, 1024, 1024, nullptr, 0, 0, 0, 0, 0);
  gemm_bt<3><<<dim3(64, 8, 1), 256, 0, stream>>>(x_bf, Wvt, bv, vt_bf, nullptr,
      8192, 1024, 1024, nullptr, 0, 0, 0, 0, 0);

  // 3. attention -> ctx (reuses x_bf)
  attn_fwd<<<dim3(8, 16, 16), 256, 0, stream>>>(q_bf, k_bf, vt_bf, ctx);

  // 4. output projection + residual(x) -> tmp (fp32), then LN1 in place
  gemm_bt<2><<<dim3(64, 8, 1), 256, 0, stream>>>(ctx, Wot, bo, tmp, x,
      8192, 1024, 1024, nullptr, 0, 0, 0, 0, 0);
  ln_inplace<<<2048, 256, 0, stream>>>(tmp, ln1g, ln1b);

  // 5. LN2 -> x_ln (bf16) + column sums; router
  hipMemsetAsync(colsum, 0, 16 * 1024 * sizeof(float), stream);
  ln2_colsum<<<dim3(8, 16), 256, 0, stream>>>(tmp, ln2g, ln2b, xln, colsum);
  router_argmax<<<16, 64, 0, stream>>>(colsum, gate, logits, choice);

  // 6. MoE: up (gelu) then down (+attn_out residual) -> d_out
  gemm_bt<1><<<dim3(4, 32, 16), 256, 0, stream>>>(xln, Wupt, bup, h_bf, nullptr,
      512, 4096, 1024, choice, 512ll * 1024, 512ll * 4096, 0, 4096ll * 1024, 4096);
  gemm_bt<2><<<dim3(4, 8, 16), 256, 0, stream>>>(h_bf, Wdnt, bdn, d_out, tmp,
      512, 1024, 4096, choice, 512ll * 4096, 512ll * 1024, 512ll * 1024, 1024ll * 4096, 1024);
}

// Round 2
// 552.681 us; speedup vs baseline: 1.1375x; 1.1375x over previous
//
#include <hip/hip_runtime.h>

// ---------------------------------------------------------------------------
// BERT layer (attn + top-1 MoE FFN) for MI355X / gfx950.
// B=16 S=512 H=1024 I=4096 NH=16 DH=64 E=8.  bf16 MFMA (16x16x32), fp32 accum.
// R2: flash-attn rewritten — KVBLK=64, LDS-staged K/V (double-buffered,
// source-swizzled global_load_lds), 2 q-tiles/wave for ILP. 64x64 transposes.
// ---------------------------------------------------------------------------

typedef __attribute__((ext_vector_type(4))) float f32x4;
typedef __attribute__((ext_vector_type(8))) short s8v;   // 8 x bf16 bits
typedef __attribute__((ext_vector_type(4))) short s4v;   // 4 x bf16 bits
typedef unsigned short u16;

#define DEV static __device__ __forceinline__

DEV u16 f2bf(float f){
  union { float f; unsigned u; } v; v.f = f;
  unsigned r = v.u + 0x7fffu + ((v.u >> 16) & 1u);   // RNE
  return (u16)(r >> 16);
}

DEV f32x4 mfma16(s8v a, s8v b, f32x4 c){
  return __builtin_amdgcn_mfma_f32_16x16x32_bf16(a, b, c, 0, 0, 0);
}

DEV float wave_sum(float s){
#pragma unroll
  for (int o = 1; o < 64; o <<= 1) s += __shfl_xor(s, o);
  return s;
}

#define ASYNC_COPY16(g, l) \
  __builtin_amdgcn_global_load_lds((const __attribute__((address_space(1))) void*)(g), \
                                   (__attribute__((address_space(3))) void*)(l), 16, 0, 0)

// ---------------------------------------------------------------------------
// fp32 [n*8] -> bf16
__global__ __launch_bounds__(256) void cvt_bf16(const float* __restrict__ in,
                                                u16* __restrict__ out)
{
  const size_t i = ((size_t)blockIdx.x * 256 + threadIdx.x) * 8;
  f32x4 a = *(const f32x4*)&in[i];
  f32x4 b = *(const f32x4*)&in[i + 4];
  s8v o;
#pragma unroll
  for (int j = 0; j < 4; ++j){ o[j] = (short)f2bf(a[j]); o[4 + j] = (short)f2bf(b[j]); }
  *(s8v*)&out[i] = o;
}

// fp32 [R][C] -> bf16 [C][R]   (batched via blockIdx.z, stride R*C)
// 64x64 tiles: 256B coalesced fp32 reads, 128B coalesced bf16 writes.
__global__ __launch_bounds__(256) void transpose_w(const float* __restrict__ in,
                                                   u16* __restrict__ out, int R, int C)
{
  __shared__ float t[64][65];
  const size_t bs = (size_t)blockIdx.z * R * (size_t)C;
  in += bs; out += bs;
  const int c0 = blockIdx.x * 64, r0 = blockIdx.y * 64;
  const int tx = threadIdx.x & 63, ty = threadIdx.x >> 6;   // 64 x 4
#pragma unroll
  for (int j = 0; j < 64; j += 4) t[ty + j][tx] = in[(size_t)(r0 + ty + j) * C + c0 + tx];
  __syncthreads();
#pragma unroll
  for (int j = 0; j < 64; j += 4) out[(size_t)(c0 + ty + j) * R + r0 + tx] = f2bf(t[tx][ty + j]);
}

// ---------------------------------------------------------------------------
// C = A[M,K](bf16) * Bt[N,K]^T(bf16) + bias;   128x128 tile, 4 waves, BK=32.
// MODE 0: bf16 out   1: gelu->bf16 out   2: fp32 out + residual
// MODE 3: bf16 scatter to vt[b][h][d][s]  (B=16,NH=16,DH=64,S=512)
template<int MODE>
__global__ __launch_bounds__(256, 2) void gemm_bt(
    const u16* __restrict__ A, const u16* __restrict__ Bt,
    const float* __restrict__ bias, void* __restrict__ outp,
    const float* __restrict__ resid, int M, int N, int K,
    const int* __restrict__ choice,
    long aBatch, long outBatch, long residBatch, long btExpert, long biasExpert)
{
  const int z = blockIdx.z;
  if (choice){
    const int e = choice[z];
    Bt   += (size_t)e * btExpert;
    bias += (size_t)e * biasExpert;
  }
  A += (size_t)z * aBatch;

  const int tid = threadIdx.x;
  const int lane = tid & 63, wid = tid >> 6;
  const int hi = lane >> 4, l15 = lane & 15;
  const int wr = wid >> 1, wc = wid & 1;
  const long row0 = (long)blockIdx.x * 128;
  const long col0 = (long)blockIdx.y * 128;

  __shared__ __align__(16) u16 lA[128 * 32];
  __shared__ __align__(16) u16 lB[128 * 32];

  f32x4 acc[4][4];
#pragma unroll
  for (int i = 0; i < 4; ++i)
#pragma unroll
    for (int j = 0; j < 4; ++j) acc[i][j] = f32x4{0.f, 0.f, 0.f, 0.f};

  const int c1 = tid, c2 = tid + 256;
  const u16* sA1 = A  + (row0 + (c1 >> 2)) * (size_t)K + (c1 & 3) * 8;
  const u16* sA2 = A  + (row0 + (c2 >> 2)) * (size_t)K + (c2 & 3) * 8;
  const u16* sB1 = Bt + (col0 + (c1 >> 2)) * (size_t)K + (c1 & 3) * 8;
  const u16* sB2 = Bt + (col0 + (c2 >> 2)) * (size_t)K + (c2 & 3) * 8;
  u16* dA1 = &lA[c1 * 8]; u16* dA2 = &lA[c2 * 8];
  u16* dB1 = &lB[c1 * 8]; u16* dB2 = &lB[c2 * 8];

  for (int kt = 0; kt < K; kt += 32){
    ASYNC_COPY16(sA1, dA1);
    ASYNC_COPY16(sA2, dA2);
    ASYNC_COPY16(sB1, dB1);
    ASYNC_COPY16(sB2, dB2);
    sA1 += 32; sA2 += 32; sB1 += 32; sB2 += 32;
    asm volatile("s_waitcnt vmcnt(0)" ::: "memory");
    __syncthreads();

    s8v af[4], bf[4];
#pragma unroll
    for (int mi = 0; mi < 4; ++mi)
      af[mi] = *(const s8v*)&lA[(wr * 64 + mi * 16 + l15) * 32 + hi * 8];
#pragma unroll
    for (int ni = 0; ni < 4; ++ni)
      bf[ni] = *(const s8v*)&lB[(wc * 64 + ni * 16 + l15) * 32 + hi * 8];
#pragma unroll
    for (int mi = 0; mi < 4; ++mi)
#pragma unroll
      for (int ni = 0; ni < 4; ++ni)
        acc[mi][ni] = mfma16(af[mi], bf[ni], acc[mi][ni]);
    __syncthreads();
  }

#pragma unroll
  for (int mi = 0; mi < 4; ++mi){
    const long rowb = row0 + wr * 64 + mi * 16 + hi * 4;
#pragma unroll
    for (int ni = 0; ni < 4; ++ni){
      const long col = col0 + wc * 64 + ni * 16 + l15;
      const float bv = bias[col];
#pragma unroll
      for (int r = 0; r < 4; ++r){
        const long row = rowb + r;
        float v = acc[mi][ni][r] + bv;
        if (MODE == 2){
          float* o = (float*)outp + (size_t)z * outBatch;
          const float* rs = resid + (size_t)z * residBatch;
          o[row * N + col] = v + rs[row * N + col];
        } else if (MODE == 0){
          u16* o = (u16*)outp + (size_t)z * outBatch;
          o[row * N + col] = f2bf(v);
        } else if (MODE == 1){
          u16* o = (u16*)outp + (size_t)z * outBatch;
          const float gv = 0.5f * v * (1.0f + erff(v * 0.70710678118654752f));
          o[row * N + col] = f2bf(gv);
        } else {                       // MODE 3: vt[b][h][d][s]
          const int bb = (int)(row >> 9), ss = (int)(row & 511);
          const int hh = (int)(col >> 6), dd = (int)(col & 63);
          ((u16*)outp)[(((size_t)(bb * 16 + hh)) * 64 + dd) * 512 + ss] = f2bf(v);
        }
      }
    }
  }
}

// ---------------------------------------------------------------------------
// Flash attention, swapped form (S^T = K*Q^T; softmax state lane-local, q=l15).
// Block = (b, h, 128 q rows).  4 waves x 2 q-tiles (ILP-2 softmax chains).
// KVBLK=64: K[64][64] and V^T[64][64] double-buffered in LDS via
// global_load_lds with XOR-swizzled SOURCE (seg ^= row&7) so the b128
// fragment reads are bank-balanced (8 words/bank).  P^T via per-wave LDS.
__global__ __launch_bounds__(256) void attn_fwd(
    const u16* __restrict__ qb, const u16* __restrict__ kb,
    const u16* __restrict__ vt, u16* __restrict__ ctx)
{
  const int tid = threadIdx.x;
  const int lane = tid & 63, wid = tid >> 6;
  const int hi = lane >> 4, l15 = lane & 15;
  const int h = blockIdx.y, b = blockIdx.z;
  const int q0 = blockIdx.x * 128 + wid * 32;

  const u16* kp0 = kb + (size_t)b * 512 * 1024 + h * 64;     // K rows, stride 1024
  const u16* vp0 = vt + ((size_t)(b * 16 + h)) * 64 * 512;   // V^T rows, stride 512

  __shared__ __align__(16) u16 lK[2][64 * 64];
  __shared__ __align__(16) u16 lV[2][64 * 64];
  __shared__ __align__(16) u16 lP[4][2][16][72];

  // staging: 256 threads x 2 insts x 16B = 8KB tile; LDS dest linear,
  // global source column pre-swizzled (rule #21 both-sides pattern).
#define STAGE(bsel, k0s) do { \
  _Pragma("unroll") \
  for (int i = 0; i < 2; ++i){ \
    const int idx = i * 256 + tid; \
    const int row = idx >> 3, seg = idx & 7; \
    const int sc = ((seg ^ (row & 7)) << 3); \
    ASYNC_COPY16(kp0 + (size_t)((k0s) + row) * 1024 + sc, &lK[bsel][idx * 8]); \
    ASYNC_COPY16(vp0 + (size_t)row * 512 + (k0s) + sc,    &lV[bsel][idx * 8]); \
  } \
} while (0)

  // Q fragments for this wave's 2 q-tiles (persistent in VGPRs)
  const u16* qp = qb + ((size_t)b * 512 + q0) * 1024 + h * 64;
  s8v qf[2][2];
#pragma unroll
  for (int qt = 0; qt < 2; ++qt)
#pragma unroll
    for (int st = 0; st < 2; ++st)
      qf[qt][st] = *(const s8v*)&qp[(size_t)(qt * 16 + l15) * 1024 + st * 32 + hi * 8];

  f32x4 o[2][4];
#pragma unroll
  for (int qt = 0; qt < 2; ++qt)
#pragma unroll
    for (int mi = 0; mi < 4; ++mi) o[qt][mi] = f32x4{0.f, 0.f, 0.f, 0.f};
  float mrun[2] = {-3e38f, -3e38f}, lrun[2] = {0.f, 0.f};

  STAGE(0, 0);
  __syncthreads();   // drains vmcnt

  for (int t = 0; t < 8; ++t){
    const int buf = t & 1;
    if (t < 7) STAGE(buf ^ 1, (t + 1) * 64);   // prefetch next tile

    // ---- S^T = K * Q^T : 16 MFMA (2 qt x 4 kt x 2 k-steps)
    f32x4 s[2][4];
#pragma unroll
    for (int qt = 0; qt < 2; ++qt)
#pragma unroll
      for (int kt = 0; kt < 4; ++kt) s[qt][kt] = f32x4{0.f, 0.f, 0.f, 0.f};
#pragma unroll
    for (int st = 0; st < 2; ++st){
      s8v kf[4];
#pragma unroll
      for (int kt = 0; kt < 4; ++kt){
        const int row = kt * 16 + l15;
        kf[kt] = *(const s8v*)&lK[buf][row * 64 + (((st * 4 + hi) ^ (row & 7)) << 3)];
      }
#pragma unroll
      for (int qt = 0; qt < 2; ++qt)
#pragma unroll
        for (int kt = 0; kt < 4; ++kt)
          s[qt][kt] = mfma16(kf[kt], qf[qt][st], s[qt][kt]);
    }

    // ---- online softmax (2 independent chains)
#pragma unroll
    for (int qt = 0; qt < 2; ++qt){
      float mx = s[qt][0][0];
#pragma unroll
      for (int kt = 0; kt < 4; ++kt)
#pragma unroll
        for (int r = 0; r < 4; ++r) mx = fmaxf(mx, s[qt][kt][r]);
      mx *= 0.125f;
      mx = fmaxf(mx, __shfl_xor(mx, 16));
      mx = fmaxf(mx, __shfl_xor(mx, 32));
      const float mnew = fmaxf(mrun[qt], mx);
      const float alpha = __expf(mrun[qt] - mnew);
      mrun[qt] = mnew;
      float ps = 0.f;
#pragma unroll
      for (int kt = 0; kt < 4; ++kt){
        s4v pk;
#pragma unroll
        for (int r = 0; r < 4; ++r){
          const float p = __expf(s[qt][kt][r] * 0.125f - mnew);
          ps += p; pk[r] = (short)f2bf(p);
        }
        *(s4v*)&lP[wid][qt][l15][kt * 16 + 4 * hi] = pk;
      }
      ps += __shfl_xor(ps, 16);
      ps += __shfl_xor(ps, 32);
      lrun[qt] = lrun[qt] * alpha + ps;
#pragma unroll
      for (int mi = 0; mi < 4; ++mi)
#pragma unroll
        for (int r = 0; r < 4; ++r) o[qt][mi][r] *= alpha;
    }

    // ---- O^T += V^T * P : 16 MFMA
#pragma unroll
    for (int ks = 0; ks < 2; ++ks){
      s8v vf[4];
#pragma unroll
      for (int mi = 0; mi < 4; ++mi){
        const int row = mi * 16 + l15;
        vf[mi] = *(const s8v*)&lV[buf][row * 64 + (((ks * 4 + hi) ^ (row & 7)) << 3)];
      }
#pragma unroll
      for (int qt = 0; qt < 2; ++qt){
        const s8v pf = *(const s8v*)&lP[wid][qt][l15][ks * 32 + 8 * hi];
#pragma unroll
        for (int mi = 0; mi < 4; ++mi)
          o[qt][mi] = mfma16(vf[mi], pf, o[qt][mi]);
      }
    }
    __syncthreads();   // staged tile ready; everyone done reading buf
  }
#undef STAGE

#pragma unroll
  for (int qt = 0; qt < 2; ++qt){
    const float inv = 1.f / lrun[qt];
    u16* cp = ctx + ((size_t)b * 512 + q0 + qt * 16 + l15) * 1024 + h * 64;
#pragma unroll
    for (int mi = 0; mi < 4; ++mi)
#pragma unroll
      for (int r = 0; r < 4; ++r)
        cp[mi * 16 + 4 * hi + r] = f2bf(o[qt][mi][r] * inv);
  }
}

// ---------------------------------------------------------------------------
// LayerNorm in place (fp32), one wave per 1024-col row.
__global__ __launch_bounds__(256, 2) void ln_inplace(float* __restrict__ x,
    const float* __restrict__ g, const float* __restrict__ be)
{
  const int row = blockIdx.x * 4 + (threadIdx.x >> 6);
  const int lane = threadIdx.x & 63;
  float* p = x + (size_t)row * 1024;
  f32x4 v[4];
#pragma unroll
  for (int c = 0; c < 4; ++c) v[c] = *(const f32x4*)&p[c * 256 + lane * 4];
  float s = 0.f;
#pragma unroll
  for (int c = 0; c < 4; ++c){ s += v[c][0] + v[c][1] + v[c][2] + v[c][3]; }
  const float mu = wave_sum(s) * (1.f / 1024.f);
  float s2 = 0.f;
#pragma unroll
  for (int c = 0; c < 4; ++c)
#pragma unroll
    for (int j = 0; j < 4; ++j){ const float d = v[c][j] - mu; s2 += d * d; }
  const float rs = rsqrtf(wave_sum(s2) * (1.f / 1024.f) + 1e-12f);
#pragma unroll
  for (int c = 0; c < 4; ++c){
    const f32x4 gg = *(const f32x4*)&g[c * 256 + lane * 4];
    const f32x4 bb = *(const f32x4*)&be[c * 256 + lane * 4];
    f32x4 ov;
#pragma unroll
    for (int j = 0; j < 4; ++j) ov[j] = (v[c][j] - mu) * rs * gg[j] + bb[j];
    *(f32x4*)&p[c * 256 + lane * 4] = ov;
  }
}

// LN2 -> bf16 x_ln, plus fp32 per-(b,col) column sums for the router.
__global__ __launch_bounds__(256, 2) void ln2_colsum(
    const float* __restrict__ attn, const float* __restrict__ g, const float* __restrict__ be,
    u16* __restrict__ xln, float* __restrict__ colsum)
{
  const int b = blockIdx.y;
  const int wid = threadIdx.x >> 6, lane = threadIdx.x & 63;
  __shared__ float cacc[1024];
  for (int i = threadIdx.x; i < 1024; i += 256) cacc[i] = 0.f;
  __syncthreads();
  float acc[16];
#pragma unroll
  for (int i = 0; i < 16; ++i) acc[i] = 0.f;
  const int rbase = b * 512 + blockIdx.x * 64 + wid * 16;
  for (int rr = 0; rr < 16; ++rr){
    const float* p = attn + (size_t)(rbase + rr) * 1024;
    f32x4 v[4];
#pragma unroll
    for (int c = 0; c < 4; ++c) v[c] = *(const f32x4*)&p[c * 256 + lane * 4];
    float s = 0.f;
#pragma unroll
    for (int c = 0; c < 4; ++c) s += v[c][0] + v[c][1] + v[c][2] + v[c][3];
    const float mu = wave_sum(s) * (1.f / 1024.f);
    float s2 = 0.f;
#pragma unroll
    for (int c = 0; c < 4; ++c)
#pragma unroll
      for (int j = 0; j < 4; ++j){ const float d = v[c][j] - mu; s2 += d * d; }
    const float rs = rsqrtf(wave_sum(s2) * (1.f / 1024.f) + 1e-12f);
    u16* op = xln + (size_t)(rbase + rr) * 1024;
#pragma unroll
    for (int c = 0; c < 4; ++c){
      const f32x4 gg = *(const f32x4*)&g[c * 256 + lane * 4];
      const f32x4 bb = *(const f32x4*)&be[c * 256 + lane * 4];
      s4v ov;
#pragma unroll
      for (int j = 0; j < 4; ++j){
        const float y = (v[c][j] - mu) * rs * gg[j] + bb[j];
        acc[c * 4 + j] += y;
        ov[j] = (short)f2bf(y);
      }
      *(s4v*)&op[c * 256 + lane * 4] = ov;
    }
  }
#pragma unroll
  for (int c = 0; c < 4; ++c)
#pragma unroll
    for (int j = 0; j < 4; ++j)
      atomicAdd(&cacc[c * 256 + lane * 4 + j], acc[c * 4 + j]);
  __syncthreads();
  for (int i = threadIdx.x; i < 1024; i += 256) atomicAdd(&colsum[b * 1024 + i], cacc[i]);
}

// logits[b][e] = (1/S) * sum_h colsum[b][h]*gate[h][e]; argmax -> choice.
__global__ void router_argmax(const float* __restrict__ colsum, const float* __restrict__ gate,
                              float* __restrict__ logits, int* __restrict__ choice)
{
  const int b = blockIdx.x, lane = threadIdx.x;   // 64 threads
  float pa[8];
#pragma unroll
  for (int e = 0; e < 8; ++e) pa[e] = 0.f;
  for (int it = 0; it < 16; ++it){
    const int hh = it * 64 + lane;
    const float c = colsum[b * 1024 + hh];
    const float* gp = gate + (size_t)hh * 8;
#pragma unroll
    for (int e = 0; e < 8; ++e) pa[e] += c * gp[e];
  }
#pragma unroll
  for (int e = 0; e < 8; ++e) pa[e] = wave_sum(pa[e]);
  if (lane == 0){
    float best = -3e38f; int bi = 0;
#pragma unroll
    for (int e = 0; e < 8; ++e){
      const float lg = pa[e] * (1.f / 512.f);
      logits[b * 8 + e] = lg;
      if (lg > best){ best = lg; bi = e; }   // strict > keeps first max (jnp.argmax)
    }
    choice[b] = bi;
  }
}

// ---------------------------------------------------------------------------
extern "C" void kernel_launch(void* const* d_in, const int* in_sizes, int n_in,
                              void* d_out, int out_size, void* d_ws, size_t ws_size,
                              hipStream_t stream)
{
  const float* x    = (const float*)d_in[0];
  const float* Wq   = (const float*)d_in[1];
  const float* bq   = (const float*)d_in[2];
  const float* Wk   = (const float*)d_in[3];
  const float* bk   = (const float*)d_in[4];
  const float* Wv   = (const float*)d_in[5];
  const float* bv   = (const float*)d_in[6];
  const float* Wo   = (const float*)d_in[7];
  const float* bo   = (const float*)d_in[8];
  const float* ln1g = (const float*)d_in[9];
  const float* ln1b = (const float*)d_in[10];
  const float* ln2g = (const float*)d_in[11];
  const float* ln2b = (const float*)d_in[12];
  const float* gate = (const float*)d_in[13];
  const float* Wup  = (const float*)d_in[14];
  const float* bup  = (const float*)d_in[15];
  const float* Wdn  = (const float*)d_in[16];
  const float* bdn  = (const float*)d_in[17];

  size_t off = 0;
  char* wsb = (char*)d_ws;
  auto take = [&](size_t n) -> void* {
    void* p = wsb + off; off += (n + 255) & ~(size_t)255; return p;
  };
  u16*   x_bf  = (u16*)take(8192ull * 1024 * 2);          // later: ctx
  u16*   Wqt   = (u16*)take(1024ull * 1024 * 2);
  u16*   Wkt   = (u16*)take(1024ull * 1024 * 2);
  u16*   Wvt   = (u16*)take(1024ull * 1024 * 2);
  u16*   Wot   = (u16*)take(1024ull * 1024 * 2);
  u16*   q_bf  = (u16*)take(8192ull * 1024 * 2);          // later: x_ln
  u16*   k_bf  = (u16*)take(8192ull * 1024 * 2);
  u16*   vt_bf = (u16*)take(8192ull * 1024 * 2);
  float* tmp   = (float*)take(8192ull * 1024 * 4);        // pre-LN1 -> attn_out
  u16*   Wupt  = (u16*)take(8ull * 4096 * 1024 * 2);
  u16*   Wdnt  = (u16*)take(8ull * 1024 * 4096 * 2);
  u16*   h_bf  = (u16*)take(8192ull * 4096 * 2);
  float* colsum = (float*)take(16ull * 1024 * 4);
  int*   choice = (int*)take(256);

  u16* ctx = x_bf;     // x_bf dead after QKV GEMMs
  u16* xln = q_bf;     // q_bf dead after attention
  float* logits = (float*)d_out + 8388608;

  // 1. convert + transpose
  cvt_bf16<<<4096, 256, 0, stream>>>(x, x_bf);
  transpose_w<<<dim3(16, 16, 1), 256, 0, stream>>>(Wq,  Wqt,  1024, 1024);
  transpose_w<<<dim3(16, 16, 1), 256, 0, stream>>>(Wk,  Wkt,  1024, 1024);
  transpose_w<<<dim3(16, 16, 1), 256, 0, stream>>>(Wv,  Wvt,  1024, 1024);
  transpose_w<<<dim3(16, 16, 1), 256, 0, stream>>>(Wo,  Wot,  1024, 1024);
  transpose_w<<<dim3(64, 16, 8), 256, 0, stream>>>(Wup, Wupt, 1024, 4096);
  transpose_w<<<dim3(16, 64, 8), 256, 0, stream>>>(Wdn, Wdnt, 4096, 1024);

  // 2. QKV projections
  gemm_bt<0><<<dim3(64, 8, 1), 256, 0, stream>>>(x_bf, Wqt, bq, q_bf,  nullptr,
      8192, 1024, 1024, nullptr, 0, 0, 0, 0, 0);
  gemm_bt<0><<<dim3(64, 8, 1), 256, 0, stream>>>(x_bf, Wkt, bk, k_bf,  nullptr,
      8192, 1024, 1024, nullptr, 0, 0, 0, 0, 0);
  gemm_bt<3><<<dim3(64, 8, 1), 256, 0, stream>>>(x_bf, Wvt, bv, vt_bf, nullptr,
      8192, 1024, 1024, nullptr, 0, 0, 0, 0, 0);

  // 3. attention -> ctx (reuses x_bf)
  attn_fwd<<<dim3(4, 16, 16), 256, 0, stream>>>(q_bf, k_bf, vt_bf, ctx);

  // 4. output projection + residual(x) -> tmp (fp32), then LN1 in place
  gemm_bt<2><<<dim3(64, 8, 1), 256, 0, stream>>>(ctx, Wot, bo, tmp, x,
      8192, 1024, 1024, nullptr, 0, 0, 0, 0, 0);
  ln_inplace<<<2048, 256, 0, stream>>>(tmp, ln1g, ln1b);

  // 5. LN2 -> x_ln (bf16) + column sums; router
  hipMemsetAsync(colsum, 0, 16 * 1024 * sizeof(float), stream);
  ln2_colsum<<<dim3(8, 16), 256, 0, stream>>>(tmp, ln2g, ln2b, xln, colsum);
  router_argmax<<<16, 64, 0, stream>>>(colsum, gate, logits, choice);

  // 6. MoE: up (gelu) then down (+attn_out residual) -> d_out
  gemm_bt<1><<<dim3(4, 32, 16), 256, 0, stream>>>(xln, Wupt, bup, h_bf, nullptr,
      512, 4096, 1024, choice, 512ll * 1024, 512ll * 4096, 0, 4096ll * 1024, 4096);
  gemm_bt<2><<<dim3(4, 8, 16), 256, 0, stream>>>(h_bf, Wdnt, bdn, d_out, tmp,
      512, 1024, 4096, choice, 512ll * 4096, 512ll * 1024, 512ll * 1024, 1024ll * 4096, 1024);
}

// Round 3
// 535.032 us; speedup vs baseline: 1.1750x; 1.0330x over previous
//
#include <hip/hip_runtime.h>

// ---------------------------------------------------------------------------
// BERT layer (attn + top-1 MoE FFN) for MI355X / gfx950.
// B=16 S=512 H=1024 I=4096 NH=16 DH=64 E=8.  bf16 MFMA (16x16x32), fp32 accum.
// R3: gemm_bt -> 2-phase double-buffered pipeline (prefetch overlapped, one
// barrier/K-step); bijective XCD swizzle on MoE GEMMs; QKV fused into one
// GEMM (MODE 4); LN1+LN2+colsum fused.
// ---------------------------------------------------------------------------

typedef __attribute__((ext_vector_type(4))) float f32x4;
typedef __attribute__((ext_vector_type(8))) short s8v;   // 8 x bf16 bits
typedef __attribute__((ext_vector_type(4))) short s4v;   // 4 x bf16 bits
typedef unsigned short u16;

#define DEV static __device__ __forceinline__

DEV u16 f2bf(float f){
  union { float f; unsigned u; } v; v.f = f;
  unsigned r = v.u + 0x7fffu + ((v.u >> 16) & 1u);   // RNE
  return (u16)(r >> 16);
}

DEV f32x4 mfma16(s8v a, s8v b, f32x4 c){
  return __builtin_amdgcn_mfma_f32_16x16x32_bf16(a, b, c, 0, 0, 0);
}

DEV float wave_sum(float s){
#pragma unroll
  for (int o = 1; o < 64; o <<= 1) s += __shfl_xor(s, o);
  return s;
}

#define ASYNC_COPY16(g, l) \
  __builtin_amdgcn_global_load_lds((const __attribute__((address_space(1))) void*)(g), \
                                   (__attribute__((address_space(3))) void*)(l), 16, 0, 0)

// ---------------------------------------------------------------------------
// fp32 [n*8] -> bf16
__global__ __launch_bounds__(256) void cvt_bf16(const float* __restrict__ in,
                                                u16* __restrict__ out)
{
  const size_t i = ((size_t)blockIdx.x * 256 + threadIdx.x) * 8;
  f32x4 a = *(const f32x4*)&in[i];
  f32x4 b = *(const f32x4*)&in[i + 4];
  s8v o;
#pragma unroll
  for (int j = 0; j < 4; ++j){ o[j] = (short)f2bf(a[j]); o[4 + j] = (short)f2bf(b[j]); }
  *(s8v*)&out[i] = o;
}

// fp32 [R][C] -> bf16 [C][R]   (batched via blockIdx.z, stride R*C)
__global__ __launch_bounds__(256) void transpose_w(const float* __restrict__ in,
                                                   u16* __restrict__ out, int R, int C)
{
  __shared__ float t[64][65];
  const size_t bs = (size_t)blockIdx.z * R * (size_t)C;
  in += bs; out += bs;
  const int c0 = blockIdx.x * 64, r0 = blockIdx.y * 64;
  const int tx = threadIdx.x & 63, ty = threadIdx.x >> 6;   // 64 x 4
#pragma unroll
  for (int j = 0; j < 64; j += 4) t[ty + j][tx] = in[(size_t)(r0 + ty + j) * C + c0 + tx];
  __syncthreads();
#pragma unroll
  for (int j = 0; j < 64; j += 4) out[(size_t)(c0 + ty + j) * R + r0 + tx] = f2bf(t[tx][ty + j]);
}

// ---------------------------------------------------------------------------
// C = A[M,K](bf16) * Bt[N,K]^T(bf16) + bias;  128x128 tile, 4 waves, BK=32,
// double-buffered LDS with prefetch overlap (T3 minimum 2-phase).
// MODE 0: bf16 out   1: gelu->bf16 out   2: fp32 out + residual
// MODE 3: bf16 scatter to vt[b][h][d][s]
// MODE 4: fused QKV epilogue (cols 0-1023 -> outp, 1024-2047 -> out2,
//         2048-3071 -> vt-scatter to out3); bias is 3072-wide concat.
// SWZ: bijective XCD swizzle (requires nwg % 8 == 0; guarded).
template<int MODE, bool SWZ>
__global__ __launch_bounds__(256, 2) void gemm_bt(
    const u16* __restrict__ A, const u16* __restrict__ Bt,
    const float* __restrict__ bias, void* __restrict__ outp,
    const float* __restrict__ resid, int M, int N, int K,
    const int* __restrict__ choice,
    long aBatch, long outBatch, long residBatch, long btExpert, long biasExpert,
    void* __restrict__ out2, void* __restrict__ out3)
{
  int bx, by, bz;
  if (SWZ){
    const int nx = gridDim.x, ny = gridDim.y;
    const int nwg = nx * ny * gridDim.z;
    int id = blockIdx.x + nx * (blockIdx.y + ny * blockIdx.z);
    if ((nwg & 7) == 0){ const int q = nwg >> 3; id = (id & 7) * q + (id >> 3); }
    bx = id % nx; const int r2 = id / nx; by = r2 % ny; bz = r2 / ny;
  } else {
    bx = blockIdx.x; by = blockIdx.y; bz = blockIdx.z;
  }
  const int z = bz;
  if (choice){
    const int e = choice[z];
    Bt   += (size_t)e * btExpert;
    bias += (size_t)e * biasExpert;
  }
  A += (size_t)z * aBatch;

  const int tid = threadIdx.x;
  const int lane = tid & 63, wid = tid >> 6;
  const int hi = lane >> 4, l15 = lane & 15;
  const int wr = wid >> 1, wc = wid & 1;
  const long row0 = (long)bx * 128;
  const long col0 = (long)by * 128;

  __shared__ __align__(16) u16 lA[2][128 * 32];
  __shared__ __align__(16) u16 lB[2][128 * 32];

  f32x4 acc[4][4];
#pragma unroll
  for (int i = 0; i < 4; ++i)
#pragma unroll
    for (int j = 0; j < 4; ++j) acc[i][j] = f32x4{0.f, 0.f, 0.f, 0.f};

  const int c1 = tid, c2 = tid + 256;
  const u16* sA1 = A  + (row0 + (c1 >> 2)) * (size_t)K + (c1 & 3) * 8;
  const u16* sA2 = A  + (row0 + (c2 >> 2)) * (size_t)K + (c2 & 3) * 8;
  const u16* sB1 = Bt + (col0 + (c1 >> 2)) * (size_t)K + (c1 & 3) * 8;
  const u16* sB2 = Bt + (col0 + (c2 >> 2)) * (size_t)K + (c2 & 3) * 8;

#define GSTAGE(bsel) do { \
  ASYNC_COPY16(sA1, &lA[bsel][c1 * 8]); \
  ASYNC_COPY16(sA2, &lA[bsel][c2 * 8]); \
  ASYNC_COPY16(sB1, &lB[bsel][c1 * 8]); \
  ASYNC_COPY16(sB2, &lB[bsel][c2 * 8]); \
  sA1 += 32; sA2 += 32; sB1 += 32; sB2 += 32; \
} while (0)

  const int nk = K >> 5;
  GSTAGE(0);
  __syncthreads();                      // vmcnt(0) drain: tile 0 ready

  for (int t = 0; t < nk; ++t){
    const int cur = t & 1;
    if (t + 1 < nk) GSTAGE(cur ^ 1);    // prefetch next tile (in flight
                                        // during this tile's compute)
    s8v af[4], bfr[4];
#pragma unroll
    for (int mi = 0; mi < 4; ++mi)
      af[mi] = *(const s8v*)&lA[cur][(wr * 64 + mi * 16 + l15) * 32 + hi * 8];
#pragma unroll
    for (int ni = 0; ni < 4; ++ni)
      bfr[ni] = *(const s8v*)&lB[cur][(wc * 64 + ni * 16 + l15) * 32 + hi * 8];
#pragma unroll
    for (int mi = 0; mi < 4; ++mi)
#pragma unroll
      for (int ni = 0; ni < 4; ++ni)
        acc[mi][ni] = mfma16(af[mi], bfr[ni], acc[mi][ni]);
    __syncthreads();                    // one vmcnt(0)+barrier per K-step
  }
#undef GSTAGE

#pragma unroll
  for (int mi = 0; mi < 4; ++mi){
    const long rowb = row0 + wr * 64 + mi * 16 + hi * 4;
#pragma unroll
    for (int ni = 0; ni < 4; ++ni){
      const long col = col0 + wc * 64 + ni * 16 + l15;
      const float bv = bias[col];
#pragma unroll
      for (int r = 0; r < 4; ++r){
        const long row = rowb + r;
        float v = acc[mi][ni][r] + bv;
        if (MODE == 2){
          float* o = (float*)outp + (size_t)z * outBatch;
          const float* rs = resid + (size_t)z * residBatch;
          o[row * N + col] = v + rs[row * N + col];
        } else if (MODE == 0){
          u16* o = (u16*)outp + (size_t)z * outBatch;
          o[row * N + col] = f2bf(v);
        } else if (MODE == 1){
          u16* o = (u16*)outp + (size_t)z * outBatch;
          const float gv = 0.5f * v * (1.0f + erff(v * 0.70710678118654752f));
          o[row * N + col] = f2bf(gv);
        } else if (MODE == 3){          // vt[b][h][d][s]
          const int bb = (int)(row >> 9), ss = (int)(row & 511);
          const int hh = (int)(col >> 6), dd = (int)(col & 63);
          ((u16*)outp)[(((size_t)(bb * 16 + hh)) * 64 + dd) * 512 + ss] = f2bf(v);
        } else {                        // MODE 4: fused QKV
          const int seg = (int)(col >> 10), lc = (int)(col & 1023);
          const u16 bv16 = f2bf(v);
          if (seg == 0)      ((u16*)outp)[row * 1024 + lc] = bv16;
          else if (seg == 1) ((u16*)out2)[row * 1024 + lc] = bv16;
          else {
            const int bb = (int)(row >> 9), ss = (int)(row & 511);
            const int hh = lc >> 6, dd = lc & 63;
            ((u16*)out3)[(((size_t)(bb * 16 + hh)) * 64 + dd) * 512 + ss] = bv16;
          }
        }
      }
    }
  }
}

// ---------------------------------------------------------------------------
// Flash attention, swapped form (S^T = K*Q^T; softmax state lane-local, q=l15).
// Block = (b, h, 128 q rows).  4 waves x 2 q-tiles (ILP-2 softmax chains).
__global__ __launch_bounds__(256) void attn_fwd(
    const u16* __restrict__ qb, const u16* __restrict__ kb,
    const u16* __restrict__ vt, u16* __restrict__ ctx)
{
  const int tid = threadIdx.x;
  const int lane = tid & 63, wid = tid >> 6;
  const int hi = lane >> 4, l15 = lane & 15;
  const int h = blockIdx.y, b = blockIdx.z;
  const int q0 = blockIdx.x * 128 + wid * 32;

  const u16* kp0 = kb + (size_t)b * 512 * 1024 + h * 64;     // K rows, stride 1024
  const u16* vp0 = vt + ((size_t)(b * 16 + h)) * 64 * 512;   // V^T rows, stride 512

  __shared__ __align__(16) u16 lK[2][64 * 64];
  __shared__ __align__(16) u16 lV[2][64 * 64];
  __shared__ __align__(16) u16 lP[4][2][16][72];

#define STAGE(bsel, k0s) do { \
  _Pragma("unroll") \
  for (int i = 0; i < 2; ++i){ \
    const int idx = i * 256 + tid; \
    const int row = idx >> 3, seg = idx & 7; \
    const int sc = ((seg ^ (row & 7)) << 3); \
    ASYNC_COPY16(kp0 + (size_t)((k0s) + row) * 1024 + sc, &lK[bsel][idx * 8]); \
    ASYNC_COPY16(vp0 + (size_t)row * 512 + (k0s) + sc,    &lV[bsel][idx * 8]); \
  } \
} while (0)

  const u16* qp = qb + ((size_t)b * 512 + q0) * 1024 + h * 64;
  s8v qf[2][2];
#pragma unroll
  for (int qt = 0; qt < 2; ++qt)
#pragma unroll
    for (int st = 0; st < 2; ++st)
      qf[qt][st] = *(const s8v*)&qp[(size_t)(qt * 16 + l15) * 1024 + st * 32 + hi * 8];

  f32x4 o[2][4];
#pragma unroll
  for (int qt = 0; qt < 2; ++qt)
#pragma unroll
    for (int mi = 0; mi < 4; ++mi) o[qt][mi] = f32x4{0.f, 0.f, 0.f, 0.f};
  float mrun[2] = {-3e38f, -3e38f}, lrun[2] = {0.f, 0.f};

  STAGE(0, 0);
  __syncthreads();

  for (int t = 0; t < 8; ++t){
    const int buf = t & 1;
    if (t < 7) STAGE(buf ^ 1, (t + 1) * 64);

    f32x4 s[2][4];
#pragma unroll
    for (int qt = 0; qt < 2; ++qt)
#pragma unroll
      for (int kt = 0; kt < 4; ++kt) s[qt][kt] = f32x4{0.f, 0.f, 0.f, 0.f};
#pragma unroll
    for (int st = 0; st < 2; ++st){
      s8v kf[4];
#pragma unroll
      for (int kt = 0; kt < 4; ++kt){
        const int row = kt * 16 + l15;
        kf[kt] = *(const s8v*)&lK[buf][row * 64 + (((st * 4 + hi) ^ (row & 7)) << 3)];
      }
#pragma unroll
      for (int qt = 0; qt < 2; ++qt)
#pragma unroll
        for (int kt = 0; kt < 4; ++kt)
          s[qt][kt] = mfma16(kf[kt], qf[qt][st], s[qt][kt]);
    }

#pragma unroll
    for (int qt = 0; qt < 2; ++qt){
      float mx = s[qt][0][0];
#pragma unroll
      for (int kt = 0; kt < 4; ++kt)
#pragma unroll
        for (int r = 0; r < 4; ++r) mx = fmaxf(mx, s[qt][kt][r]);
      mx *= 0.125f;
      mx = fmaxf(mx, __shfl_xor(mx, 16));
      mx = fmaxf(mx, __shfl_xor(mx, 32));
      const float mnew = fmaxf(mrun[qt], mx);
      const float alpha = __expf(mrun[qt] - mnew);
      mrun[qt] = mnew;
      float ps = 0.f;
#pragma unroll
      for (int kt = 0; kt < 4; ++kt){
        s4v pk;
#pragma unroll
        for (int r = 0; r < 4; ++r){
          const float p = __expf(s[qt][kt][r] * 0.125f - mnew);
          ps += p; pk[r] = (short)f2bf(p);
        }
        *(s4v*)&lP[wid][qt][l15][kt * 16 + 4 * hi] = pk;
      }
      ps += __shfl_xor(ps, 16);
      ps += __shfl_xor(ps, 32);
      lrun[qt] = lrun[qt] * alpha + ps;
#pragma unroll
      for (int mi = 0; mi < 4; ++mi)
#pragma unroll
        for (int r = 0; r < 4; ++r) o[qt][mi][r] *= alpha;
    }

#pragma unroll
    for (int ks = 0; ks < 2; ++ks){
      s8v vf[4];
#pragma unroll
      for (int mi = 0; mi < 4; ++mi){
        const int row = mi * 16 + l15;
        vf[mi] = *(const s8v*)&lV[buf][row * 64 + (((ks * 4 + hi) ^ (row & 7)) << 3)];
      }
#pragma unroll
      for (int qt = 0; qt < 2; ++qt){
        const s8v pf = *(const s8v*)&lP[wid][qt][l15][ks * 32 + 8 * hi];
#pragma unroll
        for (int mi = 0; mi < 4; ++mi)
          o[qt][mi] = mfma16(vf[mi], pf, o[qt][mi]);
      }
    }
    __syncthreads();
  }
#undef STAGE

#pragma unroll
  for (int qt = 0; qt < 2; ++qt){
    const float inv = 1.f / lrun[qt];
    u16* cp = ctx + ((size_t)b * 512 + q0 + qt * 16 + l15) * 1024 + h * 64;
#pragma unroll
    for (int mi = 0; mi < 4; ++mi)
#pragma unroll
      for (int r = 0; r < 4; ++r)
        cp[mi * 16 + 4 * hi + r] = f2bf(o[qt][mi][r] * inv);
  }
}

// ---------------------------------------------------------------------------
// Fused LN1 (in place, fp32) + LN2 -> bf16 xln + router column sums.
__global__ __launch_bounds__(256, 2) void ln12_colsum(
    float* __restrict__ t, const float* __restrict__ g1, const float* __restrict__ b1,
    const float* __restrict__ g2, const float* __restrict__ b2,
    u16* __restrict__ xln, float* __restrict__ colsum)
{
  const int b = blockIdx.y;
  const int wid = threadIdx.x >> 6, lane = threadIdx.x & 63;
  __shared__ float cacc[1024];
  for (int i = threadIdx.x; i < 1024; i += 256) cacc[i] = 0.f;
  __syncthreads();
  float acc[16];
#pragma unroll
  for (int i = 0; i < 16; ++i) acc[i] = 0.f;
  const int rbase = b * 512 + blockIdx.x * 64 + wid * 16;
  for (int rr = 0; rr < 16; ++rr){
    float* p = t + (size_t)(rbase + rr) * 1024;
    f32x4 v[4];
#pragma unroll
    for (int c = 0; c < 4; ++c) v[c] = *(const f32x4*)&p[c * 256 + lane * 4];
    // LN1
    float s = 0.f;
#pragma unroll
    for (int c = 0; c < 4; ++c) s += v[c][0] + v[c][1] + v[c][2] + v[c][3];
    const float mu = wave_sum(s) * (1.f / 1024.f);
    float s2 = 0.f;
#pragma unroll
    for (int c = 0; c < 4; ++c)
#pragma unroll
      for (int j = 0; j < 4; ++j){ const float d = v[c][j] - mu; s2 += d * d; }
    const float rs = rsqrtf(wave_sum(s2) * (1.f / 1024.f) + 1e-12f);
    float y1s = 0.f;
#pragma unroll
    for (int c = 0; c < 4; ++c){
      const f32x4 gg = *(const f32x4*)&g1[c * 256 + lane * 4];
      const f32x4 bb = *(const f32x4*)&b1[c * 256 + lane * 4];
#pragma unroll
      for (int j = 0; j < 4; ++j){
        v[c][j] = (v[c][j] - mu) * rs * gg[j] + bb[j];
        y1s += v[c][j];
      }
      *(f32x4*)&p[c * 256 + lane * 4] = v[c];      // attn_out (resid for down)
    }
    // LN2 on y1
    const float mu2 = wave_sum(y1s) * (1.f / 1024.f);
    float s22 = 0.f;
#pragma unroll
    for (int c = 0; c < 4; ++c)
#pragma unroll
      for (int j = 0; j < 4; ++j){ const float d = v[c][j] - mu2; s22 += d * d; }
    const float rs2 = rsqrtf(wave_sum(s22) * (1.f / 1024.f) + 1e-12f);
    u16* op = xln + (size_t)(rbase + rr) * 1024;
#pragma unroll
    for (int c = 0; c < 4; ++c){
      const f32x4 gg = *(const f32x4*)&g2[c * 256 + lane * 4];
      const f32x4 bb = *(const f32x4*)&b2[c * 256 + lane * 4];
      s4v ov;
#pragma unroll
      for (int j = 0; j < 4; ++j){
        const float y = (v[c][j] - mu2) * rs2 * gg[j] + bb[j];
        acc[c * 4 + j] += y;
        ov[j] = (short)f2bf(y);
      }
      *(s4v*)&op[c * 256 + lane * 4] = ov;
    }
  }
#pragma unroll
  for (int c = 0; c < 4; ++c)
#pragma unroll
    for (int j = 0; j < 4; ++j)
      atomicAdd(&cacc[c * 256 + lane * 4 + j], acc[c * 4 + j]);
  __syncthreads();
  for (int i = threadIdx.x; i < 1024; i += 256) atomicAdd(&colsum[b * 1024 + i], cacc[i]);
}

// logits[b][e] = (1/S) * sum_h colsum[b][h]*gate[h][e]; argmax -> choice.
__global__ void router_argmax(const float* __restrict__ colsum, const float* __restrict__ gate,
                              float* __restrict__ logits, int* __restrict__ choice)
{
  const int b = blockIdx.x, lane = threadIdx.x;   // 64 threads
  float pa[8];
#pragma unroll
  for (int e = 0; e < 8; ++e) pa[e] = 0.f;
  for (int it = 0; it < 16; ++it){
    const int hh = it * 64 + lane;
    const float c = colsum[b * 1024 + hh];
    const float* gp = gate + (size_t)hh * 8;
#pragma unroll
    for (int e = 0; e < 8; ++e) pa[e] += c * gp[e];
  }
#pragma unroll
  for (int e = 0; e < 8; ++e) pa[e] = wave_sum(pa[e]);
  if (lane == 0){
    float best = -3e38f; int bi = 0;
#pragma unroll
    for (int e = 0; e < 8; ++e){
      const float lg = pa[e] * (1.f / 512.f);
      logits[b * 8 + e] = lg;
      if (lg > best){ best = lg; bi = e; }   // strict > keeps first max (jnp.argmax)
    }
    choice[b] = bi;
  }
}

// ---------------------------------------------------------------------------
extern "C" void kernel_launch(void* const* d_in, const int* in_sizes, int n_in,
                              void* d_out, int out_size, void* d_ws, size_t ws_size,
                              hipStream_t stream)
{
  const float* x    = (const float*)d_in[0];
  const float* Wq   = (const float*)d_in[1];
  const float* bq   = (const float*)d_in[2];
  const float* Wk   = (const float*)d_in[3];
  const float* bk   = (const float*)d_in[4];
  const float* Wv   = (const float*)d_in[5];
  const float* bv   = (const float*)d_in[6];
  const float* Wo   = (const float*)d_in[7];
  const float* bo   = (const float*)d_in[8];
  const float* ln1g = (const float*)d_in[9];
  const float* ln1b = (const float*)d_in[10];
  const float* ln2g = (const float*)d_in[11];
  const float* ln2b = (const float*)d_in[12];
  const float* gate = (const float*)d_in[13];
  const float* Wup  = (const float*)d_in[14];
  const float* bup  = (const float*)d_in[15];
  const float* Wdn  = (const float*)d_in[16];
  const float* bdn  = (const float*)d_in[17];

  size_t off = 0;
  char* wsb = (char*)d_ws;
  auto take = [&](size_t n) -> void* {
    void* p = wsb + off; off += (n + 255) & ~(size_t)255; return p;
  };
  u16*   x_bf  = (u16*)take(8192ull * 1024 * 2);          // later: ctx
  u16*   Wqt   = (u16*)take(1024ull * 1024 * 2);          // Wqt/Wkt/Wvt contiguous
  u16*   Wkt   = (u16*)take(1024ull * 1024 * 2);
  u16*   Wvt   = (u16*)take(1024ull * 1024 * 2);
  u16*   Wot   = (u16*)take(1024ull * 1024 * 2);
  u16*   q_bf  = (u16*)take(8192ull * 1024 * 2);          // later: x_ln
  u16*   k_bf  = (u16*)take(8192ull * 1024 * 2);
  u16*   vt_bf = (u16*)take(8192ull * 1024 * 2);
  float* tmp   = (float*)take(8192ull * 1024 * 4);        // pre-LN1 -> attn_out
  u16*   Wupt  = (u16*)take(8ull * 4096 * 1024 * 2);
  u16*   Wdnt  = (u16*)take(8ull * 1024 * 4096 * 2);
  u16*   h_bf  = (u16*)take(8192ull * 4096 * 2);
  float* colsum = (float*)take(16ull * 1024 * 4);
  int*   choice = (int*)take(256);
  float* qkvb  = (float*)take(3072 * 4);                  // concat bq|bk|bv

  u16* ctx = x_bf;     // x_bf dead after QKV GEMM
  u16* xln = q_bf;     // q_bf dead after attention
  float* logits = (float*)d_out + 8388608;

  // 1. convert + transpose (+ bias concat for fused QKV)
  cvt_bf16<<<4096, 256, 0, stream>>>(x, x_bf);
  transpose_w<<<dim3(16, 16, 1), 256, 0, stream>>>(Wq,  Wqt,  1024, 1024);
  transpose_w<<<dim3(16, 16, 1), 256, 0, stream>>>(Wk,  Wkt,  1024, 1024);
  transpose_w<<<dim3(16, 16, 1), 256, 0, stream>>>(Wv,  Wvt,  1024, 1024);
  transpose_w<<<dim3(16, 16, 1), 256, 0, stream>>>(Wo,  Wot,  1024, 1024);
  transpose_w<<<dim3(64, 16, 8), 256, 0, stream>>>(Wup, Wupt, 1024, 4096);
  transpose_w<<<dim3(16, 64, 8), 256, 0, stream>>>(Wdn, Wdnt, 4096, 1024);
  hipMemcpyAsync(qkvb,        bq, 1024 * 4, hipMemcpyDeviceToDevice, stream);
  hipMemcpyAsync(qkvb + 1024, bk, 1024 * 4, hipMemcpyDeviceToDevice, stream);
  hipMemcpyAsync(qkvb + 2048, bv, 1024 * 4, hipMemcpyDeviceToDevice, stream);

  // 2. fused QKV projection (weights Wqt|Wkt|Wvt contiguous = [3072][1024])
  gemm_bt<4, false><<<dim3(64, 24, 1), 256, 0, stream>>>(x_bf, Wqt, qkvb, q_bf,
      nullptr, 8192, 3072, 1024, nullptr, 0, 0, 0, 0, 0, k_bf, vt_bf);

  // 3. attention -> ctx (reuses x_bf)
  attn_fwd<<<dim3(4, 16, 16), 256, 0, stream>>>(q_bf, k_bf, vt_bf, ctx);

  // 4. output projection + residual(x) -> tmp (fp32), then fused LN1/LN2
  gemm_bt<2, false><<<dim3(64, 8, 1), 256, 0, stream>>>(ctx, Wot, bo, tmp, x,
      8192, 1024, 1024, nullptr, 0, 0, 0, 0, 0, nullptr, nullptr);
  hipMemsetAsync(colsum, 0, 16 * 1024 * sizeof(float), stream);
  ln12_colsum<<<dim3(8, 16), 256, 0, stream>>>(tmp, ln1g, ln1b, ln2g, ln2b, xln, colsum);
  router_argmax<<<16, 64, 0, stream>>>(colsum, gate, logits, choice);

  // 5. MoE: up (gelu) then down (+attn_out residual) -> d_out
  gemm_bt<1, true><<<dim3(4, 32, 16), 256, 0, stream>>>(xln, Wupt, bup, h_bf, nullptr,
      512, 4096, 1024, choice, 512ll * 1024, 512ll * 4096, 0, 4096ll * 1024, 4096,
      nullptr, nullptr);
  gemm_bt<2, true><<<dim3(4, 8, 16), 256, 0, stream>>>(h_bf, Wdnt, bdn, d_out, tmp,
      512, 1024, 4096, choice, 512ll * 4096, 512ll * 1024, 512ll * 1024, 1024ll * 4096, 1024,
      nullptr, nullptr);
}